// Round 7
// baseline (75.893 us; speedup 1.0000x reference)
//
#include <hip/hip_runtime.h>

// Problem constants (from setup_inputs): N=32, D=32, S=32, B=15, m=128
#define N_ 32
#define D_ 32
#define S_ 32
#define M_ 128
#define MM_ (M_ * M_)
#define INV_M (1.0f / 128.0f)
#define INV_M2 (1.0f / (128.0f * 128.0f))

typedef float f32x4 __attribute__((ext_vector_type(4)));
typedef __bf16 bf16x8 __attribute__((ext_vector_type(8)));

// Workspace layout (float offsets). Total ~10.3M floats = ~39 MiB (ws is 256 MiB).
#define WS_ROWSUM  0         // [N*D][128]  rowsum[nd*128+i] = sum_j x[i][j]
#define WS_COLSUM  131072    // [N*D][128]  colsum[nd*128+j] = sum_i x[i][j]
#define WS_DIAG    262144    // [N*D][128]
#define WS_SUMDIAG 393216    // [N*D]
#define WS_TOT     394240    // [N*D]
#define WS_RV      395264    // [N*S][128]  (includes K + bias)
#define WS_CV      526336    // [N*S][128]
#define WS_DG      657408    // [N*S][128]  (includes diag_bias)
#define WS_WBF16   788480    // bf16 [64 rows][40]: rows 0-31 = W10[s][d], 32-63 = W11[s][d]
#define WS_CSP     789760    // colsum partials [n][rg][d][j] : 32*8*32*128 floats
#define WS_SDP     1838336   // sumdiag partials [n][rg][d] : 8192
#define WS_TOTP    1846528   // tot partials [n][rg][d] : 8192
#define WS_XT      1854720   // bf16 [n][pos=i*128+j][d] : 16,777,216 bf16 (32 MiB)

__device__ __forceinline__ unsigned short f2bf(float f) {
    unsigned u = __float_as_uint(f);
    u += 0x7fffu + ((u >> 16) & 1u);          // round-to-nearest-even
    return (unsigned short)(u >> 16);
}

// ---------------- Kernel P: single pass over x ----------------
// Block = (n, rowgroup rg of 16 rows), 256 blocks x 512 thr, XCD-swizzled by n&7.
// Thread owns position (gi, jj) per chunk, loads all 32 d (wave: 256B coalesced),
// writes bf16 xT[pos][d] (64B/pos), accumulates rowsum/colsum/diag partials.
__global__ __launch_bounds__(512, 2) void eq2_prep(const float* __restrict__ x,
                                                   float* __restrict__ ws) {
    int blk = blockIdx.x;
    int n   = (blk & 7) + 8 * (blk >> 6);
    int rg  = (blk >> 3) & 7;
    int R0  = rg * 16;

    int t    = threadIdx.x;
    int jj   = t & 127;
    int q    = t >> 7;                 // 0..3
    int lane = t & 63;
    int w    = t >> 6;                 // wave 0..7; row li = 4c+(w>>1), half = w&1

    const float* xn = x + (size_t)n * (D_ * MM_);
    unsigned short* xt = (unsigned short*)(ws + WS_XT) + (size_t)n * 16384 * 32;

    __shared__ float lds_row[16][32][2];
    __shared__ float lds_diag[16][32];
    __shared__ float lds_cs[4][8][128];

    float cacc[32];
#pragma unroll
    for (int d = 0; d < 32; ++d) cacc[d] = 0.f;

    for (int c = 0; c < 4; ++c) {
        int li = 4 * c + q;
        int gi = R0 + li;
        const float* src = xn + gi * M_ + jj;

        float v[32];
#pragma unroll
        for (int d = 0; d < 32; ++d) v[d] = src[(size_t)d * MM_];

        // xT store: 32 bf16 = 64B per position
        {
            unsigned u[16];
#pragma unroll
            for (int k = 0; k < 16; ++k)
                u[k] = (unsigned)f2bf(v[2 * k]) | ((unsigned)f2bf(v[2 * k + 1]) << 16);
            uint4* dst = (uint4*)(xt + (size_t)(gi * 128 + jj) * 32);
            uint4 a = {u[0], u[1], u[2], u[3]};
            uint4 b = {u[4], u[5], u[6], u[7]};
            uint4 cc = {u[8], u[9], u[10], u[11]};
            uint4 dd = {u[12], u[13], u[14], u[15]};
            dst[0] = a; dst[1] = b; dst[2] = cc; dst[3] = dd;
        }

        // colsum accumulate (j fixed per thread)
#pragma unroll
        for (int d = 0; d < 32; ++d) cacc[d] += v[d];

        // rowsum: per-d wave reduction (wave = half-row)
#pragma unroll
        for (int d = 0; d < 32; ++d) {
            float r = v[d];
            for (int msk = 1; msk < 64; msk <<= 1) r += __shfl_xor(r, msk, 64);
            if (lane == 0) lds_row[li][d][w & 1] = r;
        }

        // diag thread for row gi
        if (jj == gi) {
            float* diag = ws + WS_DIAG;
#pragma unroll
            for (int d = 0; d < 32; ++d) {
                diag[(n * D_ + d) * M_ + gi] = v[d];
                lds_diag[li][d] = v[d];
            }
        }
    }
    __syncthreads();

    // rowsum global + tot/sumdiag partials
    {
        int li = t >> 5, d = t & 31;   // t<512 covers all
        float rsum = lds_row[li][d][0] + lds_row[li][d][1];
        (ws + WS_ROWSUM)[(n * D_ + d) * M_ + R0 + li] = rsum;
    }
    if (t < 32) {
        int d = t;
        float tp = 0.f, sp = 0.f;
        for (int li = 0; li < 16; ++li) {
            tp += lds_row[li][d][0] + lds_row[li][d][1];
            sp += lds_diag[li][d];
        }
        (ws + WS_TOTP)[(n * 8 + rg) * 32 + d] = tp;
        (ws + WS_SDP)[(n * 8 + rg) * 32 + d] = sp;
    }

    // colsum partials: fold 4 q-slots via LDS, 8 d at a time
    for (int g = 0; g < 4; ++g) {
        __syncthreads();
#pragma unroll
        for (int k = 0; k < 8; ++k) lds_cs[q][k][jj] = cacc[g * 8 + k];
        __syncthreads();
#pragma unroll
        for (int r = 0; r < 2; ++r) {
            int idx = t + 512 * r;     // 0..1023
            int d8 = idx >> 7, j2 = idx & 127;
            float s = lds_cs[0][d8][j2] + lds_cs[1][d8][j2]
                    + lds_cs[2][d8][j2] + lds_cs[3][d8][j2];
            (ws + WS_CSP)[(size_t)((n * 8 + rg) * 32 + g * 8 + d8) * 128 + j2] = s;
        }
    }
}

// ---------------- Kernel F: fold per-rowgroup partials ----------------
__global__ __launch_bounds__(128) void eq2_foldcs(float* __restrict__ ws) {
    int lid = blockIdx.x;              // 1024 = (n,d), XCD-swizzled
    int n   = (lid & 7) + 8 * (lid >> 8);
    int d   = (lid >> 3) & 31;
    int j   = threadIdx.x;

    const float* csp = ws + WS_CSP;
    float s = 0.f;
    for (int rg = 0; rg < 8; ++rg)
        s += csp[(size_t)((n * 8 + rg) * 32 + d) * 128 + j];
    (ws + WS_COLSUM)[(n * D_ + d) * M_ + j] = s;

    if (j == 0) {
        float sd = 0.f, tt = 0.f;
        for (int rg = 0; rg < 8; ++rg) {
            sd += (ws + WS_SDP)[(n * 8 + rg) * 32 + d];
            tt += (ws + WS_TOTP)[(n * 8 + rg) * 32 + d];
        }
        (ws + WS_SUMDIAG)[n * D_ + d] = sd;
        (ws + WS_TOT)[n * D_ + d]     = tt;
    }
}

// ---------------- Kernel B: contract reductions with coefs over d ----------------
__global__ __launch_bounds__(128) void eq2_combine(const float* __restrict__ coefs,
                                                   const float* __restrict__ bias,
                                                   const float* __restrict__ diag_bias,
                                                   float* __restrict__ ws) {
    int b = blockIdx.x;
    int n = b >> 5, s = b & 31;
    int i = threadIdx.x;              // 0..127

    const float* rowsum  = ws + WS_ROWSUM;
    const float* colsum  = ws + WS_COLSUM;
    const float* diag    = ws + WS_DIAG;
    const float* sumdiag = ws + WS_SUMDIAG;
    const float* tot     = ws + WS_TOT;

    float rv = 0.f, cv = 0.f, dg = 0.f, kk = 0.f;
    for (int d = 0; d < D_; ++d) {
        const float* cf = coefs + (d * S_ + s) * 15;   // uniform -> s_load
        float rs = rowsum[(n * D_ + d) * M_ + i];
        float c2 = colsum[(n * D_ + d) * M_ + i];
        float dv = diag[(n * D_ + d) * M_ + i];
        float sd = sumdiag[n * D_ + d];
        float tt = tot[n * D_ + d];
        rv += (cf[5] * c2 + cf[6] * rs) * INV_M + cf[11] * dv;          // op6,7,12
        cv += (cf[7] * c2 + cf[8] * rs) * INV_M + cf[12] * dv;          // op8,9,13
        dg += cf[0] * dv + (cf[1] * sd + cf[2] * rs + cf[3] * c2) * INV_M
              + cf[4] * tt * INV_M2;                                    // op1..5
        kk += cf[13] * sd * INV_M + cf[14] * tt * INV_M2;               // op14,15
    }
    ws[WS_RV + (n * S_ + s) * M_ + i] = rv + kk + bias[s];
    ws[WS_CV + (n * S_ + s) * M_ + i] = cv;
    ws[WS_DG + (n * S_ + s) * M_ + i] = dg + diag_bias[s];

    // pack dense coefs once: bf16, transposed to [s][d] rows (stride 40), W11 at rows 32+
    if (n == 0 && i < 32) {
        int d = i;
        unsigned short* wsbf = (unsigned short*)(ws + WS_WBF16);
        const float* cf = coefs + (d * S_ + s) * 15;
        wsbf[s * 40 + d]        = f2bf(cf[9]);
        wsbf[(32 + s) * 40 + d] = f2bf(cf[10]);
    }
}

// ---------------- Kernel C: dense part via MFMA, B-frags direct from xT ----------------
// Per n: Y = W10*X, Z = W11*X (M=32 s, K=32 d, N=positions), bf16 in / f32 acc.
// Block = 512 thr = 8 waves = mirror tile-pair {A=(ti,tj), B=(tj,ti)} (or 2 diag tiles).
// B-frag: 16B/lane direct global load from xT[n][pos][d] (no LDS staging, no cvt).
// Epilogue: out = Y + Z^T(mirror) + Rv + Cv (+Dg), Z exchanged via padded LDS.
__global__ __launch_bounds__(512, 4) void eq2_main(const float* __restrict__ ws_,
                                                   float* __restrict__ out) {
    const float* ws = (const float*)__builtin_assume_aligned(ws_, 256);
    int lid = blockIdx.x;
    int n   = (lid & 7) + 8 * (lid >> 8);     // XCD-chunked swizzle
    int b   = (lid >> 3) & 31;

    int AR, AC, BR, BC, diagpair;
    if (b < 28) {
        int ti = 0, rem = b;
        while (rem >= 7 - ti) { rem -= 7 - ti; ++ti; }
        int tj = ti + 1 + rem;        // ti < tj
        AR = ti * 16; AC = tj * 16;   // tile A = (ti,tj)
        BR = tj * 16; BC = ti * 16;   // tile B = (tj,ti)
        diagpair = 0;
    } else {
        int p = b - 28;               // 0..3
        AR = AC = (2 * p) * 16;
        BR = BC = (2 * p + 1) * 16;
        diagpair = 1;
    }

    int t    = threadIdx.x;
    int w    = t >> 6;                // wave 0..7
    int lane = t & 63;
    int lg   = lane >> 4;             // 0..3 (k-octet)
    int lj   = lane & 15;

    __shared__ float trf[8 * 545];    // Z exchange, padded
    __shared__ float lds_rv[S_][32];
    __shared__ float lds_cv[S_][32];
    __shared__ float lds_dg[S_][32];

    const unsigned short* wsbf = (const unsigned short*)(ws + WS_WBF16);
    const unsigned short* xtn  = (const unsigned short*)(ws + WS_XT) + (size_t)n * 16384 * 32;

    // ---- A-fragments (W10/W11, two m-tiles) ----
    bf16x8 A10[2], A11[2];
#pragma unroll
    for (int mt = 0; mt < 2; ++mt) {
        A10[mt] = *(const bf16x8*)(wsbf + (mt * 16 + lj) * 40 + lg * 8);
        A11[mt] = *(const bf16x8*)(wsbf + (32 + mt * 16 + lj) * 40 + lg * 8);
    }

    // ---- stage rank-1 slices ----
    {
        const float* Rv = ws + WS_RV;
        const float* Cv = ws + WS_CV;
        const float* Dg = ws + WS_DG;
#pragma unroll
        for (int k = 0; k < 2; ++k) {
            int idx = k * 512 + t;    // 0..1023
            int s = idx >> 5, q = idx & 31;
            int base = (n * S_ + s) * M_;
            int ro = (q < 16) ? AR + q : BR + (q - 16);
            int co = (q < 16) ? AC + q : BC + (q - 16);
            lds_rv[s][q] = Rv[base + ro];
            lds_cv[s][q] = Cv[base + co];
            if (diagpair) lds_dg[s][q] = Dg[base + ro];
        }
    }

    // ---- MFMA: wave w -> n-tiles 4w..4w+3; B-frags from global xT ----
    f32x4 aY[4][2], aZ[4][2];
#pragma unroll
    for (int k = 0; k < 4; ++k)
#pragma unroll
        for (int mt = 0; mt < 2; ++mt) { aY[k][mt] = 0.f; aZ[k][mt] = 0.f; }

    bf16x8 Bf[4];
#pragma unroll
    for (int k = 0; k < 4; ++k) {
        int nt = w * 4 + k;
        int tt = nt >> 4, il = nt & 15;
        int Rt = tt ? BR : AR, Ct = tt ? BC : AC;
        int pos = (Rt + il) * 128 + Ct + lj;
        Bf[k] = *(const bf16x8*)(xtn + (size_t)pos * 32 + lg * 8);
    }
#pragma unroll
    for (int k = 0; k < 4; ++k) {
        aY[k][0] = __builtin_amdgcn_mfma_f32_16x16x32_bf16(A10[0], Bf[k], aY[k][0], 0, 0, 0);
        aY[k][1] = __builtin_amdgcn_mfma_f32_16x16x32_bf16(A10[1], Bf[k], aY[k][1], 0, 0, 0);
        aZ[k][0] = __builtin_amdgcn_mfma_f32_16x16x32_bf16(A11[0], Bf[k], aZ[k][0], 0, 0, 0);
        aZ[k][1] = __builtin_amdgcn_mfma_f32_16x16x32_bf16(A11[1], Bf[k], aZ[k][1], 0, 0, 0);
    }

    // ---- epilogue: 4 rounds over acc reg r; Z exchanged via LDS ----
#pragma unroll
    for (int r = 0; r < 4; ++r) {
        if (r) __syncthreads();
#pragma unroll
        for (int k = 0; k < 4; ++k) {
            int nt = w * 4 + k;
            int tt = nt >> 4, il = nt & 15;
#pragma unroll
            for (int mt = 0; mt < 2; ++mt)
                trf[(mt * 4 + lg) * 545 + tt * 272 + il * 17 + lj] = aZ[k][mt][r];
        }
        __syncthreads();
#pragma unroll
        for (int k = 0; k < 4; ++k) {
            int nt = w * 4 + k;
            int tt = nt >> 4, il = nt & 15;
            int ttp = diagpair ? tt : 1 - tt;
            int Rt = tt ? BR : AR, Ct = tt ? BC : AC;
#pragma unroll
            for (int mt = 0; mt < 2; ++mt) {
                int s = mt * 16 + 4 * lg + r;
                float zt = trf[(mt * 4 + lg) * 545 + ttp * 272 + lj * 17 + il];
                float o = aY[k][mt][r] + zt + lds_rv[s][tt * 16 + il] + lds_cv[s][tt * 16 + lj];
                if (diagpair && il == lj) o += lds_dg[s][tt * 16 + il];
                out[(size_t)(n * S_ + s) * MM_ + (Rt + il) * M_ + Ct + lj] = o;
            }
        }
    }
}

extern "C" void kernel_launch(void* const* d_in, const int* in_sizes, int n_in,
                              void* d_out, int out_size, void* d_ws, size_t ws_size,
                              hipStream_t stream) {
    const float* x         = (const float*)d_in[0];
    const float* coefs     = (const float*)d_in[1];
    const float* bias      = (const float*)d_in[2];
    const float* diag_bias = (const float*)d_in[3];
    float* out = (float*)d_out;
    float* ws  = (float*)d_ws;   // needs ~40 MiB

    hipLaunchKernelGGL(eq2_prep,    dim3(256),  dim3(512), 0, stream, x, ws);
    hipLaunchKernelGGL(eq2_foldcs,  dim3(1024), dim3(128), 0, stream, ws);
    hipLaunchKernelGGL(eq2_combine, dim3(N_ * S_), dim3(128), 0, stream, coefs, bias, diag_bias, ws);
    hipLaunchKernelGGL(eq2_main,    dim3(1024), dim3(512), 0, stream, ws, out);
}

// Round 8
// 52.726 us; speedup vs baseline: 1.4394x; 1.4394x over previous
//
#include <hip/hip_runtime.h>

// Problem constants (from setup_inputs): N=32, D=32, S=32, B=15, m=128
#define N_ 32
#define D_ 32
#define S_ 32
#define M_ 128
#define MM_ (M_ * M_)
#define INV_M (1.0f / 128.0f)
#define INV_M2 (1.0f / (128.0f * 128.0f))

typedef float f32x4 __attribute__((ext_vector_type(4)));
typedef __bf16 bf16x8 __attribute__((ext_vector_type(8)));

// Workspace layout (float offsets). Total ~790k floats = ~3 MiB.
#define WS_ROWSUM  0         // [N*D][128]
#define WS_COLSUM  131072    // [N*D][128]
#define WS_DIAG    262144    // [N*D][128]
#define WS_SUMDIAG 393216    // [N*D]
#define WS_TOT     394240    // [N*D]
#define WS_RV      395264    // [N*S][128]  (includes K + bias)
#define WS_CV      526336    // [N*S][128]
#define WS_DG      657408    // [N*S][128]  (includes diag_bias)
#define WS_WBF16   788480    // bf16 [64 rows][40]: rows 0-31 = W10[s][d], 32-63 = W11[s][d]

__device__ __forceinline__ unsigned short f2bf(float f) {
    unsigned u = __float_as_uint(f);
    u += 0x7fffu + ((u >> 16) & 1u);          // round-to-nearest-even
    return (unsigned short)(u >> 16);
}

// ---------------- Kernel A: per-(n,d) reductions (proven R1 version) ----------------
__global__ __launch_bounds__(256) void eq2_reduce(const float* __restrict__ x,
                                                  float* __restrict__ ws) {
    int nd = blockIdx.x;              // n*D + d
    int t  = threadIdx.x;
    int g  = t >> 5;                  // row group 0..7 (16 rows each)
    int j4 = t & 31;                  // float4 column group

    const float4* xp = (const float4*)(x + (size_t)nd * MM_);

    float* rowsum  = ws + WS_ROWSUM;
    float* colsum  = ws + WS_COLSUM;
    float* diag    = ws + WS_DIAG;
    float* sumdiag = ws + WS_SUMDIAG;
    float* tot     = ws + WS_TOT;

    float4 cs = {0.f, 0.f, 0.f, 0.f};
    float dsum = 0.f, ttot = 0.f;

    for (int r = 0; r < 16; ++r) {
        int i = g * 16 + r;
        float4 v = xp[i * 32 + j4];
        cs.x += v.x; cs.y += v.y; cs.z += v.z; cs.w += v.w;
        float rp = v.x + v.y + v.z + v.w;
        ttot += rp;
        int c = i - 4 * j4;           // diagonal element if 0..3
        if (c >= 0 && c < 4) {
            float dv = (c == 0) ? v.x : (c == 1) ? v.y : (c == 2) ? v.z : v.w;
            diag[nd * M_ + i] = dv;
            dsum += dv;
        }
        float rs = rp;
        for (int msk = 1; msk < 32; msk <<= 1) rs += __shfl_xor(rs, msk, 64);
        if ((t & 31) == 0) rowsum[nd * M_ + i] = rs;
    }

    __shared__ float4 cs_lds[8][32];
    __shared__ float  red[2][4];
    cs_lds[g][j4] = cs;

    for (int msk = 1; msk < 64; msk <<= 1) {
        dsum += __shfl_xor(dsum, msk, 64);
        ttot += __shfl_xor(ttot, msk, 64);
    }
    int wave = t >> 6, lane = t & 63;
    if (lane == 0) { red[0][wave] = dsum; red[1][wave] = ttot; }
    __syncthreads();

    if (t < 32) {
        float4 a = cs_lds[0][t];
        for (int gg = 1; gg < 8; ++gg) {
            float4 b = cs_lds[gg][t];
            a.x += b.x; a.y += b.y; a.z += b.z; a.w += b.w;
        }
        ((float4*)(colsum + nd * M_))[t] = a;
    }
    if (t == 0) {
        sumdiag[nd] = red[0][0] + red[0][1] + red[0][2] + red[0][3];
        tot[nd]     = red[1][0] + red[1][1] + red[1][2] + red[1][3];
    }
}

// ---------------- Kernel B: contract reductions with coefs over d ----------------
__global__ __launch_bounds__(128) void eq2_combine(const float* __restrict__ coefs,
                                                   const float* __restrict__ bias,
                                                   const float* __restrict__ diag_bias,
                                                   float* __restrict__ ws) {
    int b = blockIdx.x;
    int n = b >> 5, s = b & 31;
    int i = threadIdx.x;              // 0..127

    const float* rowsum  = ws + WS_ROWSUM;
    const float* colsum  = ws + WS_COLSUM;
    const float* diag    = ws + WS_DIAG;
    const float* sumdiag = ws + WS_SUMDIAG;
    const float* tot     = ws + WS_TOT;

    float rv = 0.f, cv = 0.f, dg = 0.f, kk = 0.f;
    for (int d = 0; d < D_; ++d) {
        const float* cf = coefs + (d * S_ + s) * 15;   // uniform -> s_load
        float rs = rowsum[(n * D_ + d) * M_ + i];
        float c2 = colsum[(n * D_ + d) * M_ + i];
        float dv = diag[(n * D_ + d) * M_ + i];
        float sd = sumdiag[n * D_ + d];
        float tt = tot[n * D_ + d];
        rv += (cf[5] * c2 + cf[6] * rs) * INV_M + cf[11] * dv;          // op6,7,12
        cv += (cf[7] * c2 + cf[8] * rs) * INV_M + cf[12] * dv;          // op8,9,13
        dg += cf[0] * dv + (cf[1] * sd + cf[2] * rs + cf[3] * c2) * INV_M
              + cf[4] * tt * INV_M2;                                    // op1..5
        kk += cf[13] * sd * INV_M + cf[14] * tt * INV_M2;               // op14,15
    }
    ws[WS_RV + (n * S_ + s) * M_ + i] = rv + kk + bias[s];
    ws[WS_CV + (n * S_ + s) * M_ + i] = cv;
    ws[WS_DG + (n * S_ + s) * M_ + i] = dg + diag_bias[s];

    // pack dense coefs once: bf16, transposed to [s][d] rows (stride 40), W11 at rows 32+
    if (n == 0 && i < 32) {
        int d = i;
        unsigned short* wsbf = (unsigned short*)(ws + WS_WBF16);
        const float* cf = coefs + (d * S_ + s) * 15;
        wsbf[s * 40 + d]        = f2bf(cf[9]);
        wsbf[(32 + s) * 40 + d] = f2bf(cf[10]);
    }
}

// ---------------- Kernel C: dense part via MFMA, B-frags gathered in registers ----------------
// Per n: Y = W10*X, Z = W11*X (M=32 s, K=32 d, N=positions), bf16 in / f32 acc.
// Block = 512 thr = 8 waves = mirror tile-pair {A=(ti,tj), B=(tj,ti)} (or 2 diag tiles).
// B-frag: each lane loads its 8 d-strided fp32 (L3-hot after eq2_reduce), packs to
// bf16x8 in registers. No LDS staging, no pre-MFMA barrier.
// Epilogue: out = Y + Z^T(mirror) + Rv + Cv (+Dg), Z exchanged via padded LDS.
__global__ __launch_bounds__(512, 2) void eq2_main(const float* __restrict__ x,
                                                   const float* __restrict__ ws_,
                                                   float* __restrict__ out) {
    const float* ws = (const float*)__builtin_assume_aligned(ws_, 256);
    int lid = blockIdx.x;
    int n   = (lid & 7) + 8 * (lid >> 8);     // XCD-chunked swizzle
    int b   = (lid >> 3) & 31;

    int AR, AC, BR, BC, diagpair;
    if (b < 28) {
        int ti = 0, rem = b;
        while (rem >= 7 - ti) { rem -= 7 - ti; ++ti; }
        int tj = ti + 1 + rem;        // ti < tj
        AR = ti * 16; AC = tj * 16;   // tile A = (ti,tj)
        BR = tj * 16; BC = ti * 16;   // tile B = (tj,ti)
        diagpair = 0;
    } else {
        int p = b - 28;               // 0..3
        AR = AC = (2 * p) * 16;
        BR = BC = (2 * p + 1) * 16;
        diagpair = 1;
    }

    int t    = threadIdx.x;
    int w    = t >> 6;                // wave 0..7
    int lane = t & 63;
    int lg   = lane >> 4;             // 0..3 (k-octet: d = lg*8+e)
    int lj   = lane & 15;

    __shared__ float trf[8 * 545];    // Z exchange, padded
    __shared__ float lds_rv[S_][32];
    __shared__ float lds_cv[S_][32];
    __shared__ float lds_dg[S_][32];

    const unsigned short* wsbf = (const unsigned short*)(ws + WS_WBF16);
    const float* xn = x + (size_t)n * (D_ * MM_);

    // ---- A-fragments (W10/W11, two m-tiles) ----
    bf16x8 A10[2], A11[2];
#pragma unroll
    for (int mt = 0; mt < 2; ++mt) {
        A10[mt] = *(const bf16x8*)(wsbf + (mt * 16 + lj) * 40 + lg * 8);
        A11[mt] = *(const bf16x8*)(wsbf + (32 + mt * 16 + lj) * 40 + lg * 8);
    }

    // ---- stage rank-1 slices ----
    {
        const float* Rv = ws + WS_RV;
        const float* Cv = ws + WS_CV;
        const float* Dg = ws + WS_DG;
#pragma unroll
        for (int k = 0; k < 2; ++k) {
            int idx = k * 512 + t;    // 0..1023
            int s = idx >> 5, q = idx & 31;
            int base = (n * S_ + s) * M_;
            int ro = (q < 16) ? AR + q : BR + (q - 16);
            int co = (q < 16) ? AC + q : BC + (q - 16);
            lds_rv[s][q] = Rv[base + ro];
            lds_cv[s][q] = Cv[base + co];
            if (diagpair) lds_dg[s][q] = Dg[base + ro];
        }
    }

    // ---- gather B-frags: 8 d-strided fp32 loads per k-tile, pack to bf16 in regs ----
    float fv[4][8];
#pragma unroll
    for (int k = 0; k < 4; ++k) {
        int nt = w * 4 + k;
        int tt = nt >> 4, il = nt & 15;
        int Rt = tt ? BR : AR, Ct = tt ? BC : AC;
        const float* src = xn + (Rt + il) * M_ + Ct + lj + (size_t)(lg * 8) * MM_;
#pragma unroll
        for (int e = 0; e < 8; ++e)
            fv[k][e] = src[(size_t)e * MM_];
    }

    bf16x8 Bf[4];
#pragma unroll
    for (int k = 0; k < 4; ++k) {
        union { unsigned u[4]; bf16x8 v; } cvt;
#pragma unroll
        for (int e = 0; e < 4; ++e)
            cvt.u[e] = (unsigned)f2bf(fv[k][2 * e]) | ((unsigned)f2bf(fv[k][2 * e + 1]) << 16);
        Bf[k] = cvt.v;
    }

    // ---- MFMA: wave w -> n-tiles 4w..4w+3 ----
    f32x4 aY[4][2], aZ[4][2];
#pragma unroll
    for (int k = 0; k < 4; ++k)
#pragma unroll
        for (int mt = 0; mt < 2; ++mt) { aY[k][mt] = 0.f; aZ[k][mt] = 0.f; }

#pragma unroll
    for (int k = 0; k < 4; ++k) {
        aY[k][0] = __builtin_amdgcn_mfma_f32_16x16x32_bf16(A10[0], Bf[k], aY[k][0], 0, 0, 0);
        aY[k][1] = __builtin_amdgcn_mfma_f32_16x16x32_bf16(A10[1], Bf[k], aY[k][1], 0, 0, 0);
        aZ[k][0] = __builtin_amdgcn_mfma_f32_16x16x32_bf16(A11[0], Bf[k], aZ[k][0], 0, 0, 0);
        aZ[k][1] = __builtin_amdgcn_mfma_f32_16x16x32_bf16(A11[1], Bf[k], aZ[k][1], 0, 0, 0);
    }

    // ---- epilogue: 4 rounds over acc reg r; Z exchanged via LDS ----
#pragma unroll
    for (int r = 0; r < 4; ++r) {
        if (r) __syncthreads();
#pragma unroll
        for (int k = 0; k < 4; ++k) {
            int nt = w * 4 + k;
            int tt = nt >> 4, il = nt & 15;
#pragma unroll
            for (int mt = 0; mt < 2; ++mt)
                trf[(mt * 4 + lg) * 545 + tt * 272 + il * 17 + lj] = aZ[k][mt][r];
        }
        __syncthreads();
#pragma unroll
        for (int k = 0; k < 4; ++k) {
            int nt = w * 4 + k;
            int tt = nt >> 4, il = nt & 15;
            int ttp = diagpair ? tt : 1 - tt;
            int Rt = tt ? BR : AR, Ct = tt ? BC : AC;
#pragma unroll
            for (int mt = 0; mt < 2; ++mt) {
                int s = mt * 16 + 4 * lg + r;
                float zt = trf[(mt * 4 + lg) * 545 + ttp * 272 + lj * 17 + il];
                float o = aY[k][mt][r] + zt + lds_rv[s][tt * 16 + il] + lds_cv[s][tt * 16 + lj];
                if (diagpair && il == lj) o += lds_dg[s][tt * 16 + il];
                out[(size_t)(n * S_ + s) * MM_ + (Rt + il) * M_ + Ct + lj] = o;
            }
        }
    }
}

extern "C" void kernel_launch(void* const* d_in, const int* in_sizes, int n_in,
                              void* d_out, int out_size, void* d_ws, size_t ws_size,
                              hipStream_t stream) {
    const float* x         = (const float*)d_in[0];
    const float* coefs     = (const float*)d_in[1];
    const float* bias      = (const float*)d_in[2];
    const float* diag_bias = (const float*)d_in[3];
    float* out = (float*)d_out;
    float* ws  = (float*)d_ws;   // needs ~3.1 MiB

    hipLaunchKernelGGL(eq2_reduce,  dim3(N_ * D_), dim3(256), 0, stream, x, ws);
    hipLaunchKernelGGL(eq2_combine, dim3(N_ * S_), dim3(128), 0, stream, coefs, bias, diag_bias, ws);
    hipLaunchKernelGGL(eq2_main,    dim3(1024), dim3(512), 0, stream, x, ws, out);
}